// Round 9
// baseline (699.261 us; speedup 1.0000x reference)
//
#include <hip/hip_runtime.h>
#include <hip/hip_fp16.h>
#include <cstdint>

#define NT 256
#define N_ATOMS_C 600000
#define BATCH_C 24000

constexpr int K_COUNTS[11] = {10000,130000,170000,160000,100000,15000,5000,2500,2500,2500,2500};
constexpr int K_STARTS[11] = {0,10000,140000,310000,470000,570000,585000,590000,592500,595000,597500};
// heavy-degree-first dispatch order
constexpr int DORD[11] = {10,9,8,7,6,5,4,3,2,1,0};

struct AdjPtrs { const int* p[10]; };

__device__ __forceinline__ float selu_f(float x) {
    const float scale = 1.0507009873554805f;
    const float alpha = 1.6732632423543772f;
    return scale * (x > 0.f ? x : alpha * expm1f(x));
}

__device__ __forceinline__ float2 up2(unsigned u) {
    const __half2 h = __builtin_bit_cast(__half2, u);
    return __half22float2(h);
}
__device__ __forceinline__ unsigned pack2(float a, float b) {
    const __half2 h = __float22half2_rn(make_float2(a, b));
    return __builtin_bit_cast(unsigned, h);
}

template<int NLD4>
__device__ __forceinline__ void load_row(const uint2* __restrict__ p, float* r) {
#pragma unroll
    for (int v = 0; v < NLD4; ++v) {
        const uint2 t = p[v];
        const float2 a = up2(t.x), b = up2(t.y);
        r[4*v] = a.x; r[4*v+1] = a.y; r[4*v+2] = b.x; r[4*v+3] = b.y;
    }
}
template<int NLD4>
__device__ __forceinline__ void add_row(const uint2* __restrict__ p, float* r) {
#pragma unroll
    for (int v = 0; v < NLD4; ++v) {
        const uint2 t = p[v];
        const float2 a = up2(t.x), b = up2(t.y);
        r[4*v] += a.x; r[4*v+1] += a.y; r[4*v+2] += b.x; r[4*v+3] += b.y;
    }
}
template<int NF, int FO>
__device__ __forceinline__ void fma_strip(const float* r, const float* __restrict__ w,
                                          float* acc) {
#pragma unroll
    for (int f = 0; f < NF; ++f)
#pragma unroll
        for (int o = 0; o < FO; ++o)
            acc[o] = fmaf(r[f], w[f * FO + o], acc[o]);
}

// block -> (degree, segment start, count, tile index within segment)
__device__ __forceinline__ void blk2deg(int blk, int& deg, int& s, int& cnt, int& tile) {
    deg = 0; s = 0; cnt = 0; tile = 0;
#pragma unroll
    for (int di = 0; di < 11; ++di) {
        const int d = DORD[di];
        const int nb = (K_COUNTS[d] + NT - 1) / NT;
        if (blk < nb) { deg = d; s = K_STARTS[d]; cnt = K_COUNTS[d]; tile = blk; return; }
        blk -= nb;
    }
}

// ---------------------------------------------------------------------------
// prep: per atom, compute z_d = x0 @ W[2(d-1)] for d=1..4 (fp16, 4x16 packed
// into a 128-B line-aligned row) and s = x0 @ Wb(own deg) + biases (fp16, 32B).
// Projection-first shrinks L1's gather rows 152B -> 32B for deg<=4 targets.
// Membership histogram (for the inverted index) is fused in.
// ---------------------------------------------------------------------------
__global__ __launch_bounds__(256) void prep_kernel(
    const float* __restrict__ x0,    // (N, 75) f32
    const float* __restrict__ W,     // (21, 75, 15)
    const float* __restrict__ bias,  // (21, 15)
    const int* __restrict__ mem,
    int* __restrict__ cnt,
    unsigned short* __restrict__ z,  // (N, 64) fp16: z1..z4 at 16-elem offsets
    unsigned short* __restrict__ srow) // (N, 16) fp16
{
    int deg, s, c, tile;
    blk2deg(blockIdx.x, deg, s, c, tile);
    const int a = tile * NT + threadIdx.x;
    if (a >= c) return;
    const int atom = s + a;

    const int wi_b = deg ? (2 * deg - 1) : 20;
    const float* Wz0 = W;
    const float* Wz1 = W + 2 * 1125;
    const float* Wz2 = W + 4 * 1125;
    const float* Wz3 = W + 6 * 1125;
    const float* Wsb = W + wi_b * 1125;

    float z0[15], z1[15], z2[15], z3[15], sa[15];
#pragma unroll
    for (int o = 0; o < 15; ++o) {
        z0[o] = 0.f; z1[o] = 0.f; z2[o] = 0.f; z3[o] = 0.f;
        sa[o] = bias[wi_b * 15 + o] + (deg ? bias[2 * (deg - 1) * 15 + o] : 0.f);
    }

    const float* xr = x0 + (size_t)atom * 75;
#pragma unroll 1
    for (int st = 0; st < 5; ++st) {
        float r[15];
#pragma unroll
        for (int j = 0; j < 15; ++j) r[j] = xr[st * 15 + j];
#pragma unroll
        for (int f = 0; f < 15; ++f) {
            const float rv = r[f];
            const int fg = st * 15 + f;
#pragma unroll
            for (int o = 0; o < 15; ++o) {
                z0[o] = fmaf(rv, Wz0[fg * 15 + o], z0[o]);
                z1[o] = fmaf(rv, Wz1[fg * 15 + o], z1[o]);
                z2[o] = fmaf(rv, Wz2[fg * 15 + o], z2[o]);
                z3[o] = fmaf(rv, Wz3[fg * 15 + o], z3[o]);
                sa[o] = fmaf(rv, Wsb[fg * 15 + o], sa[o]);
            }
        }
    }

    uint2* zp = reinterpret_cast<uint2*>(z + (size_t)atom * 64);
#define ZW(P, arr) \
    zp[P*4+0] = make_uint2(pack2(arr[0],arr[1]),  pack2(arr[2],arr[3]));   \
    zp[P*4+1] = make_uint2(pack2(arr[4],arr[5]),  pack2(arr[6],arr[7]));   \
    zp[P*4+2] = make_uint2(pack2(arr[8],arr[9]),  pack2(arr[10],arr[11])); \
    zp[P*4+3] = make_uint2(pack2(arr[12],arr[13]),pack2(arr[14],0.f));
    ZW(0, z0) ZW(1, z1) ZW(2, z2) ZW(3, z3)
#undef ZW
    uint2* sp = reinterpret_cast<uint2*>(srow + (size_t)atom * 16);
    sp[0] = make_uint2(pack2(sa[0],sa[1]),  pack2(sa[2],sa[3]));
    sp[1] = make_uint2(pack2(sa[4],sa[5]),  pack2(sa[6],sa[7]));
    sp[2] = make_uint2(pack2(sa[8],sa[9]),  pack2(sa[10],sa[11]));
    sp[3] = make_uint2(pack2(sa[12],sa[13]),pack2(sa[14],0.f));

    atomicAdd(&cnt[mem[atom]], 1);
}

// ---------------------------------------------------------------------------
// conv1: deg<=4 -> s + sum of gathered z_deg sub-rows (32B, 1 line each).
//        deg>=5 -> s + full x0-row gathers vs Wa (rare: 190K rows).
// ---------------------------------------------------------------------------
__global__ __launch_bounds__(256) void conv1_kernel(
    const float* __restrict__ x0,
    const unsigned short* __restrict__ z,
    const unsigned short* __restrict__ srow,
    const float* __restrict__ W,
    AdjPtrs adjp,
    unsigned short* __restrict__ y1)  // (N, 16) fp16
{
    int deg, s, c, tile;
    blk2deg(blockIdx.x, deg, s, c, tile);
    const int a = tile * NT + threadIdx.x;
    if (a >= c) return;
    const int atom = s + a;

    float acc[15];
    {
        const uint2* sp = reinterpret_cast<const uint2*>(srow + (size_t)atom * 16);
        float r[16];
        load_row<4>(sp, r);
#pragma unroll
        for (int o = 0; o < 15; ++o) acc[o] = r[o];
    }

    if (deg >= 1 && deg <= 4) {
        const int* ad = adjp.p[deg - 1] + (size_t)a * deg;
        int nb[4];
#pragma unroll
        for (int k = 0; k < 4; ++k) nb[k] = ad[k < deg ? k : 0];
        uint2 t[4][4];
#pragma unroll
        for (int k = 0; k < 4; ++k) {
            const uint2* p = reinterpret_cast<const uint2*>(
                z + (size_t)nb[k] * 64 + (deg - 1) * 16);
#pragma unroll
            for (int v = 0; v < 4; ++v) t[k][v] = p[v];
        }
#pragma unroll
        for (int k = 0; k < 4; ++k) {
            if (k < deg) {
                float r[16];
#pragma unroll
                for (int v = 0; v < 4; ++v) {
                    const float2 lo = up2(t[k][v].x), hi = up2(t[k][v].y);
                    r[4*v] = lo.x; r[4*v+1] = lo.y; r[4*v+2] = hi.x; r[4*v+3] = hi.y;
                }
#pragma unroll
                for (int o = 0; o < 15; ++o) acc[o] += r[o];
            }
        }
    } else if (deg >= 5) {
        const float* Wa = W + 2 * (deg - 1) * 1125;
        const int* ad = adjp.p[deg - 1] + (size_t)a * deg;
#pragma unroll 1
        for (int st = 0; st < 3; ++st) {
            float r[25];
#pragma unroll
            for (int j = 0; j < 25; ++j) r[j] = 0.f;
            for (int k = 0; k < deg; ++k) {
                const float* xr = x0 + (size_t)ad[k] * 75 + st * 25;
#pragma unroll
                for (int j = 0; j < 25; ++j) r[j] += xr[j];
            }
            fma_strip<25, 15>(r, Wa + st * 25 * 15, acc);
        }
    }

    uint2* yp = reinterpret_cast<uint2*>(y1 + (size_t)atom * 16);
    float o_[16];
#pragma unroll
    for (int o = 0; o < 16; ++o) o_[o] = (o < 15) ? selu_f(acc[o]) : 0.f;
    yp[0] = make_uint2(pack2(o_[0],o_[1]),  pack2(o_[2],o_[3]));
    yp[1] = make_uint2(pack2(o_[4],o_[5]),  pack2(o_[6],o_[7]));
    yp[2] = make_uint2(pack2(o_[8],o_[9]),  pack2(o_[10],o_[11]));
    yp[3] = make_uint2(pack2(o_[12],o_[13]),pack2(o_[14],o_[15]));
}

// ---------------------------------------------------------------------------
// Generic conv (layers 2-4): thread = atom, fp16 in/out, f32 accum.
// ---------------------------------------------------------------------------
template<int FIN, int FINP, int FO, int FOP, int FS>
__global__ __launch_bounds__(256) void conv_kernel(
    const unsigned short* __restrict__ x,  // (N, FINP) fp16
    const float* __restrict__ W,           // (21, FIN, FO)
    const float* __restrict__ bias,        // (21, FO)
    AdjPtrs adjp,
    unsigned short* __restrict__ y)        // (N, FOP) fp16
{
    static_assert(FS % 4 == 0 && FINP % 4 == 0 && FOP % 4 == 0, "");
    constexpr int NSF = FIN / FS;
    constexpr int TF  = FIN - NSF * FS;
    constexpr int TLD4 = (TF + 3) / 4;
    static_assert(NSF * FS + TLD4 * 4 <= FINP, "tail reads past row");

    int deg, s, c, tile;
    blk2deg(blockIdx.x, deg, s, c, tile);
    const int a = tile * NT + threadIdx.x;
    if (a >= c) return;
    const int atom = s + a;

    const int wi_a = (deg == 0) ? 20 : 2 * (deg - 1);
    const int wi_b = (deg == 0) ? 20 : 2 * deg - 1;
    const float* Wa = W + wi_a * FIN * FO;
    const float* Wb = W + wi_b * FIN * FO;

    float acc[FO];
#pragma unroll
    for (int o = 0; o < FO; ++o)
        acc[o] = bias[wi_b * FO + o] + ((deg > 0) ? bias[wi_a * FO + o] : 0.f);

    const int* myadj = (deg > 0) ? (adjp.p[deg - 1] + (size_t)a * deg) : nullptr;
    const uint2* selfrow = reinterpret_cast<const uint2*>(x + (size_t)atom * FINP);

#pragma unroll 1
    for (int st = 0; st < NSF; ++st) {
        const int f0 = st * FS;
        float r[FS];
        load_row<FS / 4>(selfrow + (f0 >> 2), r);
        fma_strip<FS, FO>(r, Wb + f0 * FO, acc);
        if (deg > 0) {
#pragma unroll
            for (int f = 0; f < FS; ++f) r[f] = 0.f;
            for (int k = 0; k < deg; ++k)
                add_row<FS / 4>(reinterpret_cast<const uint2*>(
                    x + (size_t)myadj[k] * FINP) + (f0 >> 2), r);
            fma_strip<FS, FO>(r, Wa + f0 * FO, acc);
        }
    }
    if constexpr (TF > 0) {
        constexpr int f0 = NSF * FS;
        float r[TLD4 * 4];
        load_row<TLD4>(selfrow + (f0 >> 2), r);
        fma_strip<TF, FO>(r, Wb + f0 * FO, acc);
        if (deg > 0) {
#pragma unroll
            for (int f = 0; f < TLD4 * 4; ++f) r[f] = 0.f;
            for (int k = 0; k < deg; ++k)
                add_row<TLD4>(reinterpret_cast<const uint2*>(
                    x + (size_t)myadj[k] * FINP) + (f0 >> 2), r);
            fma_strip<TF, FO>(r, Wa + f0 * FO, acc);
        }
    }

    float outv[FOP];
#pragma unroll
    for (int o = 0; o < FOP; ++o) outv[o] = (o < FO) ? selu_f(acc[o]) : 0.f;
    uint2* yp = reinterpret_cast<uint2*>(y + (size_t)atom * FOP);
#pragma unroll
    for (int v = 0; v < FOP / 4; ++v)
        yp[v] = make_uint2(pack2(outv[4*v], outv[4*v+1]),
                           pack2(outv[4*v+2], outv[4*v+3]));
}

// ---------------------------------------------------------------------------
// inverted-index build: zero -> (count fused in prep) -> scan -> scatter
// ---------------------------------------------------------------------------
__global__ __launch_bounds__(256) void zero_cnt_kernel(int* __restrict__ cnt) {
    const int i = blockIdx.x * NT + threadIdx.x;
    if (i < BATCH_C) cnt[i] = 0;
}
__global__ __launch_bounds__(1024) void scan_kernel(const int* __restrict__ cnt,
                                                    int* __restrict__ base,
                                                    int* __restrict__ cursor) {
    __shared__ int part[1024];
    const int tid = threadIdx.x;
    constexpr int CH = 24;
    const int i0 = tid * CH;
    int sum = 0;
    for (int j = 0; j < CH; ++j) { const int i = i0 + j; if (i < BATCH_C) sum += cnt[i]; }
    part[tid] = sum;
    __syncthreads();
    for (int off = 1; off < 1024; off <<= 1) {
        const int v = (tid >= off) ? part[tid - off] : 0;
        __syncthreads(); part[tid] += v; __syncthreads();
    }
    int run = part[tid] - sum;
    for (int j = 0; j < CH; ++j) {
        const int i = i0 + j;
        if (i < BATCH_C) { base[i] = run; cursor[i] = run; run += cnt[i]; }
    }
    if (tid == 1023) base[BATCH_C] = part[1023];
}
__global__ __launch_bounds__(256) void scatter_kernel(const int* __restrict__ mem,
                                                      int* __restrict__ cursor,
                                                      int* __restrict__ alist) {
    const int i = blockIdx.x * NT + threadIdx.x;
    if (i < N_ATOMS_C) { const int p = atomicAdd(&cursor[mem[i]], 1); alist[p] = i; }
}

// ---------------------------------------------------------------------------
// one wave per molecule: register sum/max over fp16 y4 rows, fused
// tanh -> 72x24 dense -> pairwise softmax
// ---------------------------------------------------------------------------
__global__ __launch_bounds__(256) void reduce_dense_kernel(
    const unsigned short* __restrict__ y4,  // (N, 36) fp16
    const int* __restrict__ base, const int* __restrict__ alist,
    const float* __restrict__ Wd, const float* __restrict__ bd,
    float* __restrict__ out)
{
    __shared__ float sW[72 * 24];
    __shared__ float sb[24];
    __shared__ float molf[4][72];

    const int tid = threadIdx.x;
    for (int i = tid; i < 72 * 24; i += NT) sW[i] = Wd[i];
    if (tid < 24) sb[tid] = bd[tid];
    __syncthreads();

    const int w = tid >> 6, lane = tid & 63;
    const int mol = blockIdx.x * 4 + w;
    const int b0 = base[mol], b1 = base[mol + 1];

    if (lane < 36) {
        float s = 0.f, mx = -INFINITY;
        for (int k = b0; k < b1; ++k) {
            const int atom = alist[k];
            const float v = __half2float(__builtin_bit_cast(__half,
                                y4[(size_t)atom * 36 + lane]));
            s += v; mx = fmaxf(mx, v);
        }
        molf[w][lane] = tanhf(s);
        molf[w][36 + lane] = tanhf(mx);
    }
    __syncthreads();

    if (lane < 24) {
        float l = sb[lane];
#pragma unroll
        for (int f = 0; f < 72; ++f) l += molf[w][f] * sW[f * 24 + lane];
        const float lp = __shfl_xor(l, 1);
        const float m2 = fmaxf(l, lp);
        const float e = expf(l - m2), ep = expf(lp - m2);
        out[(size_t)mol * 24 + lane] = e / (e + ep);
    }
}

// ---------------------------------------------------------------------------
extern "C" void kernel_launch(void* const* d_in, const int* in_sizes, int n_in,
                              void* d_out, int out_size, void* d_ws, size_t ws_size,
                              hipStream_t stream)
{
    const float* x0         = (const float*)d_in[0];
    const int*   membership = (const int*)d_in[2];
    AdjPtrs adj;
    for (int d = 0; d < 10; ++d) adj.p[d] = (const int*)d_in[3 + d];
    const float *W1=(const float*)d_in[13], *b1=(const float*)d_in[14];
    const float *W2=(const float*)d_in[15], *b2=(const float*)d_in[16];
    const float *W3=(const float*)d_in[17], *b3=(const float*)d_in[18];
    const float *W4=(const float*)d_in[19], *b4=(const float*)d_in[20];
    const float *Wd=(const float*)d_in[21], *bd=(const float*)d_in[22];

    // ws layout (bytes):
    //  A [0 .. 81.6M): z (N x 64 fp16 = 76.8M, dead after conv1)
    //                  then y2 = A[0..38.4M) (stride 32), y4 = A[38.4..81.6M) (stride 36)
    //  B [szA .. +38.4M): srow (9.6M) + y1 (19.2M, at +9.6M); after L2, y3 = B[0..38.4M)
    //  ints after B
    const size_t szA = 81600000;
    const size_t szB = 38400000;
    const size_t nInts = (size_t)N_ATOMS_C + (BATCH_C + 1) + BATCH_C + BATCH_C;
    if (ws_size < szA + szB + nInts * 4) return;

    char* base0 = (char*)d_ws;
    unsigned short* zbuf = (unsigned short*)base0;
    unsigned short* y2   = (unsigned short*)base0;                      // alias z (after conv1)
    unsigned short* y4   = (unsigned short*)(base0 + 38400000);         // alias z tail
    unsigned short* srow = (unsigned short*)(base0 + szA);
    unsigned short* y1   = (unsigned short*)(base0 + szA + 9600000);
    unsigned short* y3   = (unsigned short*)(base0 + szA);              // alias srow/y1 (after L2)
    int* alist  = (int*)(base0 + szA + szB);
    int* base   = alist + N_ATOMS_C;
    int* cursor = base + (BATCH_C + 1);
    int* cnt    = cursor + BATCH_C;

    int nblk = 0;
    for (int d = 0; d < 11; ++d) nblk += (K_COUNTS[d] + NT - 1) / NT;
    const int nb_atoms = (N_ATOMS_C + NT - 1) / NT;

    zero_cnt_kernel<<<(BATCH_C + NT - 1) / NT, NT, 0, stream>>>(cnt);
    prep_kernel<<<nblk, NT, 0, stream>>>(x0, W1, b1, membership, cnt, zbuf, srow);
    scan_kernel<<<1, 1024, 0, stream>>>(cnt, base, cursor);
    scatter_kernel<<<nb_atoms, NT, 0, stream>>>(membership, cursor, alist);

    conv1_kernel<<<nblk, NT, 0, stream>>>(x0, zbuf, srow, W1, adj, y1);
    conv_kernel<15,16,20,32,16><<<nblk, NT, 0, stream>>>(y1, W2, b2, adj, y2);
    conv_kernel<20,32,27,32,32><<<nblk, NT, 0, stream>>>(y2, W3, b3, adj, y3);
    conv_kernel<27,32,36,36,32><<<nblk, NT, 0, stream>>>(y3, W4, b4, adj, y4);

    reduce_dense_kernel<<<BATCH_C / 4, NT, 0, stream>>>(y4, base, alist, Wd, bd, (float*)d_out);
}

// Round 10
// 680.917 us; speedup vs baseline: 1.0269x; 1.0269x over previous
//
#include <hip/hip_runtime.h>
#include <hip/hip_fp16.h>
#include <cstdint>

#define NT 256
#define N_ATOMS_C 600000
#define BATCH_C 24000

constexpr int K_COUNTS[11] = {10000,130000,170000,160000,100000,15000,5000,2500,2500,2500,2500};
constexpr int K_STARTS[11] = {0,10000,140000,310000,470000,570000,585000,590000,592500,595000,597500};
// heavy-degree-first dispatch order
constexpr int DORD[11] = {10,9,8,7,6,5,4,3,2,1,0};

struct AdjPtrs { const int* p[10]; };

__device__ __forceinline__ float selu_f(float x) {
    const float scale = 1.0507009873554805f;
    const float alpha = 1.6732632423543772f;
    return scale * (x > 0.f ? x : alpha * expm1f(x));
}

__device__ __forceinline__ float2 up2(unsigned u) {
    const __half2 h = __builtin_bit_cast(__half2, u);
    return __half22float2(h);
}
__device__ __forceinline__ unsigned pack2(float a, float b) {
    const __half2 h = __float22half2_rn(make_float2(a, b));
    return __builtin_bit_cast(unsigned, h);
}

template<int NLD4>
__device__ __forceinline__ void load_row(const uint2* __restrict__ p, float* r) {
#pragma unroll
    for (int v = 0; v < NLD4; ++v) {
        const uint2 t = p[v];
        const float2 a = up2(t.x), b = up2(t.y);
        r[4*v] = a.x; r[4*v+1] = a.y; r[4*v+2] = b.x; r[4*v+3] = b.y;
    }
}
template<int NLD4>
__device__ __forceinline__ void add_row(const uint2* __restrict__ p, float* r) {
#pragma unroll
    for (int v = 0; v < NLD4; ++v) {
        const uint2 t = p[v];
        const float2 a = up2(t.x), b = up2(t.y);
        r[4*v] += a.x; r[4*v+1] += a.y; r[4*v+2] += b.x; r[4*v+3] += b.y;
    }
}
template<int NF, int FO>
__device__ __forceinline__ void fma_strip(const float* r, const float* __restrict__ w,
                                          float* acc) {
#pragma unroll
    for (int f = 0; f < NF; ++f)
#pragma unroll
        for (int o = 0; o < FO; ++o)
            acc[o] = fmaf(r[f], w[f * FO + o], acc[o]);
}

// block -> (degree, segment start, count, tile index within segment)
__device__ __forceinline__ void blk2deg(int blk, int& deg, int& s, int& cnt, int& tile) {
    deg = 0; s = 0; cnt = 0; tile = 0;
#pragma unroll
    for (int di = 0; di < 11; ++di) {
        const int d = DORD[di];
        const int nb = (K_COUNTS[d] + NT - 1) / NT;
        if (blk < nb) { deg = d; s = K_STARTS[d]; cnt = K_COUNTS[d]; tile = blk; return; }
        blk -= nb;
    }
}

// ---------------------------------------------------------------------------
// prep: per atom, compute z_d = x0 @ W[2(d-1)] for d=1..4 (fp16, 4x16 packed
// into a 128-B line-aligned row) and s = x0 @ Wb(own deg) + biases (fp16, 32B).
// Projection-first shrinks L1's gather rows 152B -> 32B for deg<=4 targets.
// Membership histogram (for the inverted index) is fused in.
// __launch_bounds__(256,2): 75 live accumulators need ~100 VGPR; the default
// allocation (64) scratch-spilled them (r9: FETCH +130MB, 271us).
// ---------------------------------------------------------------------------
__global__ __launch_bounds__(256, 2) void prep_kernel(
    const float* __restrict__ x0,    // (N, 75) f32
    const float* __restrict__ W,     // (21, 75, 15)
    const float* __restrict__ bias,  // (21, 15)
    const int* __restrict__ mem,
    int* __restrict__ cnt,
    unsigned short* __restrict__ z,  // (N, 64) fp16: z1..z4 at 16-elem offsets
    unsigned short* __restrict__ srow) // (N, 16) fp16
{
    int deg, s, c, tile;
    blk2deg(blockIdx.x, deg, s, c, tile);
    const int a = tile * NT + threadIdx.x;
    if (a >= c) return;
    const int atom = s + a;

    const int wi_b = deg ? (2 * deg - 1) : 20;
    const float* Wz0 = W;
    const float* Wz1 = W + 2 * 1125;
    const float* Wz2 = W + 4 * 1125;
    const float* Wz3 = W + 6 * 1125;
    const float* Wsb = W + wi_b * 1125;

    float z0[15], z1[15], z2[15], z3[15], sa[15];
#pragma unroll
    for (int o = 0; o < 15; ++o) {
        z0[o] = 0.f; z1[o] = 0.f; z2[o] = 0.f; z3[o] = 0.f;
        sa[o] = bias[wi_b * 15 + o] + (deg ? bias[2 * (deg - 1) * 15 + o] : 0.f);
    }

    const float* xr = x0 + (size_t)atom * 75;
#pragma unroll 1
    for (int st = 0; st < 5; ++st) {
        float r[15];
#pragma unroll
        for (int j = 0; j < 15; ++j) r[j] = xr[st * 15 + j];
#pragma unroll
        for (int f = 0; f < 15; ++f) {
            const float rv = r[f];
            const int fg = st * 15 + f;
#pragma unroll
            for (int o = 0; o < 15; ++o) {
                z0[o] = fmaf(rv, Wz0[fg * 15 + o], z0[o]);
                z1[o] = fmaf(rv, Wz1[fg * 15 + o], z1[o]);
                z2[o] = fmaf(rv, Wz2[fg * 15 + o], z2[o]);
                z3[o] = fmaf(rv, Wz3[fg * 15 + o], z3[o]);
                sa[o] = fmaf(rv, Wsb[fg * 15 + o], sa[o]);
            }
        }
    }

    uint2* zp = reinterpret_cast<uint2*>(z + (size_t)atom * 64);
#define ZW(P, arr) \
    zp[P*4+0] = make_uint2(pack2(arr[0],arr[1]),  pack2(arr[2],arr[3]));   \
    zp[P*4+1] = make_uint2(pack2(arr[4],arr[5]),  pack2(arr[6],arr[7]));   \
    zp[P*4+2] = make_uint2(pack2(arr[8],arr[9]),  pack2(arr[10],arr[11])); \
    zp[P*4+3] = make_uint2(pack2(arr[12],arr[13]),pack2(arr[14],0.f));
    ZW(0, z0) ZW(1, z1) ZW(2, z2) ZW(3, z3)
#undef ZW
    uint2* sp = reinterpret_cast<uint2*>(srow + (size_t)atom * 16);
    sp[0] = make_uint2(pack2(sa[0],sa[1]),  pack2(sa[2],sa[3]));
    sp[1] = make_uint2(pack2(sa[4],sa[5]),  pack2(sa[6],sa[7]));
    sp[2] = make_uint2(pack2(sa[8],sa[9]),  pack2(sa[10],sa[11]));
    sp[3] = make_uint2(pack2(sa[12],sa[13]),pack2(sa[14],0.f));

    atomicAdd(&cnt[mem[atom]], 1);
}

// ---------------------------------------------------------------------------
// conv1: deg<=4 -> s + sum of gathered z_deg sub-rows (32B, 1 line each).
//        deg>=5 -> s + full x0-row gathers vs Wa (rare: 190K rows).
// ---------------------------------------------------------------------------
__global__ __launch_bounds__(256) void conv1_kernel(
    const float* __restrict__ x0,
    const unsigned short* __restrict__ z,
    const unsigned short* __restrict__ srow,
    const float* __restrict__ W,
    AdjPtrs adjp,
    unsigned short* __restrict__ y1)  // (N, 16) fp16
{
    int deg, s, c, tile;
    blk2deg(blockIdx.x, deg, s, c, tile);
    const int a = tile * NT + threadIdx.x;
    if (a >= c) return;
    const int atom = s + a;

    float acc[15];
    {
        const uint2* sp = reinterpret_cast<const uint2*>(srow + (size_t)atom * 16);
        float r[16];
        load_row<4>(sp, r);
#pragma unroll
        for (int o = 0; o < 15; ++o) acc[o] = r[o];
    }

    if (deg >= 1 && deg <= 4) {
        const int* ad = adjp.p[deg - 1] + (size_t)a * deg;
        int nb[4];
#pragma unroll
        for (int k = 0; k < 4; ++k) nb[k] = ad[k < deg ? k : 0];
        uint2 t[4][4];
#pragma unroll
        for (int k = 0; k < 4; ++k) {
            const uint2* p = reinterpret_cast<const uint2*>(
                z + (size_t)nb[k] * 64 + (deg - 1) * 16);
#pragma unroll
            for (int v = 0; v < 4; ++v) t[k][v] = p[v];
        }
#pragma unroll
        for (int k = 0; k < 4; ++k) {
            if (k < deg) {
                float r[16];
#pragma unroll
                for (int v = 0; v < 4; ++v) {
                    const float2 lo = up2(t[k][v].x), hi = up2(t[k][v].y);
                    r[4*v] = lo.x; r[4*v+1] = lo.y; r[4*v+2] = hi.x; r[4*v+3] = hi.y;
                }
#pragma unroll
                for (int o = 0; o < 15; ++o) acc[o] += r[o];
            }
        }
    } else if (deg >= 5) {
        const float* Wa = W + 2 * (deg - 1) * 1125;
        const int* ad = adjp.p[deg - 1] + (size_t)a * deg;
#pragma unroll 1
        for (int st = 0; st < 3; ++st) {
            float r[25];
#pragma unroll
            for (int j = 0; j < 25; ++j) r[j] = 0.f;
            for (int k = 0; k < deg; ++k) {
                const float* xr = x0 + (size_t)ad[k] * 75 + st * 25;
#pragma unroll
                for (int j = 0; j < 25; ++j) r[j] += xr[j];
            }
            fma_strip<25, 15>(r, Wa + st * 25 * 15, acc);
        }
    }

    uint2* yp = reinterpret_cast<uint2*>(y1 + (size_t)atom * 16);
    float o_[16];
#pragma unroll
    for (int o = 0; o < 16; ++o) o_[o] = (o < 15) ? selu_f(acc[o]) : 0.f;
    yp[0] = make_uint2(pack2(o_[0],o_[1]),  pack2(o_[2],o_[3]));
    yp[1] = make_uint2(pack2(o_[4],o_[5]),  pack2(o_[6],o_[7]));
    yp[2] = make_uint2(pack2(o_[8],o_[9]),  pack2(o_[10],o_[11]));
    yp[3] = make_uint2(pack2(o_[12],o_[13]),pack2(o_[14],o_[15]));
}

// ---------------------------------------------------------------------------
// Generic conv (layers 2-4): thread = atom, fp16 in/out, f32 accum.
// ---------------------------------------------------------------------------
template<int FIN, int FINP, int FO, int FOP, int FS>
__global__ __launch_bounds__(256) void conv_kernel(
    const unsigned short* __restrict__ x,  // (N, FINP) fp16
    const float* __restrict__ W,           // (21, FIN, FO)
    const float* __restrict__ bias,        // (21, FO)
    AdjPtrs adjp,
    unsigned short* __restrict__ y)        // (N, FOP) fp16
{
    static_assert(FS % 4 == 0 && FINP % 4 == 0 && FOP % 4 == 0, "");
    constexpr int NSF = FIN / FS;
    constexpr int TF  = FIN - NSF * FS;
    constexpr int TLD4 = (TF + 3) / 4;
    static_assert(NSF * FS + TLD4 * 4 <= FINP, "tail reads past row");

    int deg, s, c, tile;
    blk2deg(blockIdx.x, deg, s, c, tile);
    const int a = tile * NT + threadIdx.x;
    if (a >= c) return;
    const int atom = s + a;

    const int wi_a = (deg == 0) ? 20 : 2 * (deg - 1);
    const int wi_b = (deg == 0) ? 20 : 2 * deg - 1;
    const float* Wa = W + wi_a * FIN * FO;
    const float* Wb = W + wi_b * FIN * FO;

    float acc[FO];
#pragma unroll
    for (int o = 0; o < FO; ++o)
        acc[o] = bias[wi_b * FO + o] + ((deg > 0) ? bias[wi_a * FO + o] : 0.f);

    const int* myadj = (deg > 0) ? (adjp.p[deg - 1] + (size_t)a * deg) : nullptr;
    const uint2* selfrow = reinterpret_cast<const uint2*>(x + (size_t)atom * FINP);

#pragma unroll 1
    for (int st = 0; st < NSF; ++st) {
        const int f0 = st * FS;
        float r[FS];
        load_row<FS / 4>(selfrow + (f0 >> 2), r);
        fma_strip<FS, FO>(r, Wb + f0 * FO, acc);
        if (deg > 0) {
#pragma unroll
            for (int f = 0; f < FS; ++f) r[f] = 0.f;
            for (int k = 0; k < deg; ++k)
                add_row<FS / 4>(reinterpret_cast<const uint2*>(
                    x + (size_t)myadj[k] * FINP) + (f0 >> 2), r);
            fma_strip<FS, FO>(r, Wa + f0 * FO, acc);
        }
    }
    if constexpr (TF > 0) {
        constexpr int f0 = NSF * FS;
        float r[TLD4 * 4];
        load_row<TLD4>(selfrow + (f0 >> 2), r);
        fma_strip<TF, FO>(r, Wb + f0 * FO, acc);
        if (deg > 0) {
#pragma unroll
            for (int f = 0; f < TLD4 * 4; ++f) r[f] = 0.f;
            for (int k = 0; k < deg; ++k)
                add_row<TLD4>(reinterpret_cast<const uint2*>(
                    x + (size_t)myadj[k] * FINP) + (f0 >> 2), r);
            fma_strip<TF, FO>(r, Wa + f0 * FO, acc);
        }
    }

    float outv[FOP];
#pragma unroll
    for (int o = 0; o < FOP; ++o) outv[o] = (o < FO) ? selu_f(acc[o]) : 0.f;
    uint2* yp = reinterpret_cast<uint2*>(y + (size_t)atom * FOP);
#pragma unroll
    for (int v = 0; v < FOP / 4; ++v)
        yp[v] = make_uint2(pack2(outv[4*v], outv[4*v+1]),
                           pack2(outv[4*v+2], outv[4*v+3]));
}

// ---------------------------------------------------------------------------
// inverted-index build: zero -> (count fused in prep) -> scan -> scatter
// ---------------------------------------------------------------------------
__global__ __launch_bounds__(256) void zero_cnt_kernel(int* __restrict__ cnt) {
    const int i = blockIdx.x * NT + threadIdx.x;
    if (i < BATCH_C) cnt[i] = 0;
}
__global__ __launch_bounds__(1024) void scan_kernel(const int* __restrict__ cnt,
                                                    int* __restrict__ base,
                                                    int* __restrict__ cursor) {
    __shared__ int part[1024];
    const int tid = threadIdx.x;
    constexpr int CH = 24;
    const int i0 = tid * CH;
    int sum = 0;
    for (int j = 0; j < CH; ++j) { const int i = i0 + j; if (i < BATCH_C) sum += cnt[i]; }
    part[tid] = sum;
    __syncthreads();
    for (int off = 1; off < 1024; off <<= 1) {
        const int v = (tid >= off) ? part[tid - off] : 0;
        __syncthreads(); part[tid] += v; __syncthreads();
    }
    int run = part[tid] - sum;
    for (int j = 0; j < CH; ++j) {
        const int i = i0 + j;
        if (i < BATCH_C) { base[i] = run; cursor[i] = run; run += cnt[i]; }
    }
    if (tid == 1023) base[BATCH_C] = part[1023];
}
__global__ __launch_bounds__(256) void scatter_kernel(const int* __restrict__ mem,
                                                      int* __restrict__ cursor,
                                                      int* __restrict__ alist) {
    const int i = blockIdx.x * NT + threadIdx.x;
    if (i < N_ATOMS_C) { const int p = atomicAdd(&cursor[mem[i]], 1); alist[p] = i; }
}

// ---------------------------------------------------------------------------
// one wave per molecule: register sum/max over fp16 y4 rows, fused
// tanh -> 72x24 dense -> pairwise softmax
// ---------------------------------------------------------------------------
__global__ __launch_bounds__(256) void reduce_dense_kernel(
    const unsigned short* __restrict__ y4,  // (N, 36) fp16
    const int* __restrict__ base, const int* __restrict__ alist,
    const float* __restrict__ Wd, const float* __restrict__ bd,
    float* __restrict__ out)
{
    __shared__ float sW[72 * 24];
    __shared__ float sb[24];
    __shared__ float molf[4][72];

    const int tid = threadIdx.x;
    for (int i = tid; i < 72 * 24; i += NT) sW[i] = Wd[i];
    if (tid < 24) sb[tid] = bd[tid];
    __syncthreads();

    const int w = tid >> 6, lane = tid & 63;
    const int mol = blockIdx.x * 4 + w;
    const int b0 = base[mol], b1 = base[mol + 1];

    if (lane < 36) {
        float s = 0.f, mx = -INFINITY;
        for (int k = b0; k < b1; ++k) {
            const int atom = alist[k];
            const float v = __half2float(__builtin_bit_cast(__half,
                                y4[(size_t)atom * 36 + lane]));
            s += v; mx = fmaxf(mx, v);
        }
        molf[w][lane] = tanhf(s);
        molf[w][36 + lane] = tanhf(mx);
    }
    __syncthreads();

    if (lane < 24) {
        float l = sb[lane];
#pragma unroll
        for (int f = 0; f < 72; ++f) l += molf[w][f] * sW[f * 24 + lane];
        const float lp = __shfl_xor(l, 1);
        const float m2 = fmaxf(l, lp);
        const float e = expf(l - m2), ep = expf(lp - m2);
        out[(size_t)mol * 24 + lane] = e / (e + ep);
    }
}

// ---------------------------------------------------------------------------
extern "C" void kernel_launch(void* const* d_in, const int* in_sizes, int n_in,
                              void* d_out, int out_size, void* d_ws, size_t ws_size,
                              hipStream_t stream)
{
    const float* x0         = (const float*)d_in[0];
    const int*   membership = (const int*)d_in[2];
    AdjPtrs adj;
    for (int d = 0; d < 10; ++d) adj.p[d] = (const int*)d_in[3 + d];
    const float *W1=(const float*)d_in[13], *b1=(const float*)d_in[14];
    const float *W2=(const float*)d_in[15], *b2=(const float*)d_in[16];
    const float *W3=(const float*)d_in[17], *b3=(const float*)d_in[18];
    const float *W4=(const float*)d_in[19], *b4=(const float*)d_in[20];
    const float *Wd=(const float*)d_in[21], *bd=(const float*)d_in[22];

    // ws layout (bytes):
    //  A [0 .. 81.6M): z (N x 64 fp16 = 76.8M, dead after conv1)
    //                  then y2 = A[0..38.4M) (stride 32), y4 = A[38.4..81.6M) (stride 36)
    //  B [szA .. +38.4M): srow (9.6M) + y1 (19.2M, at +9.6M); after L2, y3 = B[0..38.4M)
    //  ints after B
    const size_t szA = 81600000;
    const size_t szB = 38400000;
    const size_t nInts = (size_t)N_ATOMS_C + (BATCH_C + 1) + BATCH_C + BATCH_C;
    if (ws_size < szA + szB + nInts * 4) return;

    char* base0 = (char*)d_ws;
    unsigned short* zbuf = (unsigned short*)base0;
    unsigned short* y2   = (unsigned short*)base0;                      // alias z (after conv1)
    unsigned short* y4   = (unsigned short*)(base0 + 38400000);         // alias z tail
    unsigned short* srow = (unsigned short*)(base0 + szA);
    unsigned short* y1   = (unsigned short*)(base0 + szA + 9600000);
    unsigned short* y3   = (unsigned short*)(base0 + szA);              // alias srow/y1 (after L2)
    int* alist  = (int*)(base0 + szA + szB);
    int* base   = alist + N_ATOMS_C;
    int* cursor = base + (BATCH_C + 1);
    int* cnt    = cursor + BATCH_C;

    int nblk = 0;
    for (int d = 0; d < 11; ++d) nblk += (K_COUNTS[d] + NT - 1) / NT;
    const int nb_atoms = (N_ATOMS_C + NT - 1) / NT;

    zero_cnt_kernel<<<(BATCH_C + NT - 1) / NT, NT, 0, stream>>>(cnt);
    prep_kernel<<<nblk, NT, 0, stream>>>(x0, W1, b1, membership, cnt, zbuf, srow);
    scan_kernel<<<1, 1024, 0, stream>>>(cnt, base, cursor);
    scatter_kernel<<<nb_atoms, NT, 0, stream>>>(membership, cursor, alist);

    conv1_kernel<<<nblk, NT, 0, stream>>>(x0, zbuf, srow, W1, adj, y1);
    conv_kernel<15,16,20,32,16><<<nblk, NT, 0, stream>>>(y1, W2, b2, adj, y2);
    conv_kernel<20,32,27,32,32><<<nblk, NT, 0, stream>>>(y2, W3, b3, adj, y3);
    conv_kernel<27,32,36,36,32><<<nblk, NT, 0, stream>>>(y3, W4, b4, adj, y4);

    reduce_dense_kernel<<<BATCH_C / 4, NT, 0, stream>>>(y4, base, alist, Wd, bd, (float*)d_out);
}

// Round 11
// 679.818 us; speedup vs baseline: 1.0286x; 1.0016x over previous
//
#include <hip/hip_runtime.h>
#include <hip/hip_fp16.h>
#include <cstdint>

#define NT 256
#define N_ATOMS_C 600000
#define BATCH_C 24000

constexpr int K_COUNTS[11] = {10000,130000,170000,160000,100000,15000,5000,2500,2500,2500,2500};
constexpr int K_STARTS[11] = {0,10000,140000,310000,470000,570000,585000,590000,592500,595000,597500};
// heavy-degree-first dispatch order
constexpr int DORD[11] = {10,9,8,7,6,5,4,3,2,1,0};

struct AdjPtrs { const int* p[10]; };

__device__ __forceinline__ float selu_f(float x) {
    const float scale = 1.0507009873554805f;
    const float alpha = 1.6732632423543772f;
    return scale * (x > 0.f ? x : alpha * expm1f(x));
}

__device__ __forceinline__ float2 up2(unsigned u) {
    const __half2 h = __builtin_bit_cast(__half2, u);
    return __half22float2(h);
}
__device__ __forceinline__ unsigned pack2(float a, float b) {
    const __half2 h = __float22half2_rn(make_float2(a, b));
    return __builtin_bit_cast(unsigned, h);
}

template<int NLD4>
__device__ __forceinline__ void load_row(const uint2* __restrict__ p, float* r) {
#pragma unroll
    for (int v = 0; v < NLD4; ++v) {
        const uint2 t = p[v];
        const float2 a = up2(t.x), b = up2(t.y);
        r[4*v] = a.x; r[4*v+1] = a.y; r[4*v+2] = b.x; r[4*v+3] = b.y;
    }
}
template<int NLD4>
__device__ __forceinline__ void add_row(const uint2* __restrict__ p, float* r) {
#pragma unroll
    for (int v = 0; v < NLD4; ++v) {
        const uint2 t = p[v];
        const float2 a = up2(t.x), b = up2(t.y);
        r[4*v] += a.x; r[4*v+1] += a.y; r[4*v+2] += b.x; r[4*v+3] += b.y;
    }
}
template<int NF, int FO>
__device__ __forceinline__ void fma_strip(const float* r, const float* __restrict__ w,
                                          float* acc) {
#pragma unroll
    for (int f = 0; f < NF; ++f)
#pragma unroll
        for (int o = 0; o < FO; ++o)
            acc[o] = fmaf(r[f], w[f * FO + o], acc[o]);
}

// block -> (degree, segment start, count, tile index within segment)
__device__ __forceinline__ void blk2deg(int blk, int& deg, int& s, int& cnt, int& tile) {
    deg = 0; s = 0; cnt = 0; tile = 0;
#pragma unroll
    for (int di = 0; di < 11; ++di) {
        const int d = DORD[di];
        const int nb = (K_COUNTS[d] + NT - 1) / NT;
        if (blk < nb) { deg = d; s = K_STARTS[d]; cnt = K_COUNTS[d]; tile = blk; return; }
        blk -= nb;
    }
}

// ---------------------------------------------------------------------------
// prep: per atom, z_d = x0 @ W[2(d-1)] (d=1..4, fp16 4x16 packed per 128-B row)
// and s = x0 @ Wb(own deg) + biases (fp16, 32B). PRESSURE-FREE STRUCTURE:
// the block's rows are staged once in LDS (fp16, stride 78 shorts = odd dword
// count -> conflict-free), then the 5 projections run SEQUENTIALLY per thread
// with only 15 live accumulators each (r9/r10: 75 live accs -> scratch spill,
// 130MB extra FETCH, 271us; launch_bounds didn't fix it).
// Membership histogram fused in.
// ---------------------------------------------------------------------------
__global__ __launch_bounds__(256) void prep_kernel(
    const float* __restrict__ x0,    // (N, 75) f32
    const float* __restrict__ W,     // (21, 75, 15)
    const float* __restrict__ bias,  // (21, 15)
    const int* __restrict__ mem,
    int* __restrict__ cnt,
    unsigned short* __restrict__ z,  // (N, 64) fp16: z1..z4 at 16-elem offsets
    unsigned short* __restrict__ srow) // (N, 16) fp16
{
    __shared__ unsigned short sx[NT * 78];   // 39.9 KB; stride 78 (39 dwords, odd)

    int deg, s, c, tile;
    blk2deg(blockIdx.x, deg, s, c, tile);
    const int a0 = tile * NT;
    const int na = min(NT, c - a0);
    const int tid = threadIdx.x;

    // cooperative coalesced stage: na*75 f32 -> fp16 LDS (padded)
    const float* src = x0 + (size_t)(s + a0) * 75;
    for (int i = tid; i < na * 75; i += NT) {
        const int j = i / 75, f = i - j * 75;
        sx[j * 78 + f] = __builtin_bit_cast(unsigned short, __float2half_rn(src[i]));
    }
    __syncthreads();

    const int a = a0 + tid;
    if (a >= c) return;                      // no barriers after this point
    const int atom = s + a;

    const unsigned* row32 = reinterpret_cast<const unsigned*>(sx + tid * 78);
    const int wi_b = deg ? (2 * deg - 1) : 20;
    uint2* zp = reinterpret_cast<uint2*>(z + (size_t)atom * 64);
    uint2* sp = reinterpret_cast<uint2*>(srow + (size_t)atom * 16);

#pragma unroll 1
    for (int p = 0; p < 5; ++p) {
        const int wi = (p < 4) ? 2 * p : wi_b;
        const float* Wp = W + wi * 1125;

        float acc[15];
        if (p < 4) {
#pragma unroll
            for (int o = 0; o < 15; ++o) acc[o] = 0.f;
        } else {
#pragma unroll
            for (int o = 0; o < 15; ++o)
                acc[o] = bias[wi_b * 15 + o] + (deg ? bias[2 * (deg - 1) * 15 + o] : 0.f);
        }

        // 37 uint reads = feats 0..73, then scalar tail feat 74 (skips pad 75)
#pragma unroll 2
        for (int u = 0; u < 37; ++u) {
            const float2 fv = up2(row32[u]);
            const float* w0 = Wp + (2 * u) * 15;
#pragma unroll
            for (int o = 0; o < 15; ++o) acc[o] = fmaf(fv.x, w0[o], acc[o]);
#pragma unroll
            for (int o = 0; o < 15; ++o) acc[o] = fmaf(fv.y, w0[15 + o], acc[o]);
        }
        {
            const float fv = __half2float(__builtin_bit_cast(__half, sx[tid * 78 + 74]));
            const float* w0 = Wp + 74 * 15;
#pragma unroll
            for (int o = 0; o < 15; ++o) acc[o] = fmaf(fv, w0[o], acc[o]);
        }

        uint2* outp = (p < 4) ? (zp + p * 4) : sp;
        outp[0] = make_uint2(pack2(acc[0], acc[1]),  pack2(acc[2], acc[3]));
        outp[1] = make_uint2(pack2(acc[4], acc[5]),  pack2(acc[6], acc[7]));
        outp[2] = make_uint2(pack2(acc[8], acc[9]),  pack2(acc[10], acc[11]));
        outp[3] = make_uint2(pack2(acc[12], acc[13]), pack2(acc[14], 0.f));
    }

    atomicAdd(&cnt[mem[atom]], 1);
}

// ---------------------------------------------------------------------------
// conv1: deg<=4 -> s + sum of gathered z_deg sub-rows (32B, 1 line each).
//        deg>=5 -> s + full x0-row gathers vs Wa (rare: 190K rows).
// ---------------------------------------------------------------------------
__global__ __launch_bounds__(256) void conv1_kernel(
    const float* __restrict__ x0,
    const unsigned short* __restrict__ z,
    const unsigned short* __restrict__ srow,
    const float* __restrict__ W,
    AdjPtrs adjp,
    unsigned short* __restrict__ y1)  // (N, 16) fp16
{
    int deg, s, c, tile;
    blk2deg(blockIdx.x, deg, s, c, tile);
    const int a = tile * NT + threadIdx.x;
    if (a >= c) return;
    const int atom = s + a;

    float acc[15];
    {
        const uint2* sp = reinterpret_cast<const uint2*>(srow + (size_t)atom * 16);
        float r[16];
        load_row<4>(sp, r);
#pragma unroll
        for (int o = 0; o < 15; ++o) acc[o] = r[o];
    }

    if (deg >= 1 && deg <= 4) {
        const int* ad = adjp.p[deg - 1] + (size_t)a * deg;
        int nb[4];
#pragma unroll
        for (int k = 0; k < 4; ++k) nb[k] = ad[k < deg ? k : 0];
        uint2 t[4][4];
#pragma unroll
        for (int k = 0; k < 4; ++k) {
            const uint2* p = reinterpret_cast<const uint2*>(
                z + (size_t)nb[k] * 64 + (deg - 1) * 16);
#pragma unroll
            for (int v = 0; v < 4; ++v) t[k][v] = p[v];
        }
#pragma unroll
        for (int k = 0; k < 4; ++k) {
            if (k < deg) {
                float r[16];
#pragma unroll
                for (int v = 0; v < 4; ++v) {
                    const float2 lo = up2(t[k][v].x), hi = up2(t[k][v].y);
                    r[4*v] = lo.x; r[4*v+1] = lo.y; r[4*v+2] = hi.x; r[4*v+3] = hi.y;
                }
#pragma unroll
                for (int o = 0; o < 15; ++o) acc[o] += r[o];
            }
        }
    } else if (deg >= 5) {
        const float* Wa = W + 2 * (deg - 1) * 1125;
        const int* ad = adjp.p[deg - 1] + (size_t)a * deg;
#pragma unroll 1
        for (int st = 0; st < 3; ++st) {
            float r[25];
#pragma unroll
            for (int j = 0; j < 25; ++j) r[j] = 0.f;
            for (int k = 0; k < deg; ++k) {
                const float* xr = x0 + (size_t)ad[k] * 75 + st * 25;
#pragma unroll
                for (int j = 0; j < 25; ++j) r[j] += xr[j];
            }
            fma_strip<25, 15>(r, Wa + st * 25 * 15, acc);
        }
    }

    uint2* yp = reinterpret_cast<uint2*>(y1 + (size_t)atom * 16);
    float o_[16];
#pragma unroll
    for (int o = 0; o < 16; ++o) o_[o] = (o < 15) ? selu_f(acc[o]) : 0.f;
    yp[0] = make_uint2(pack2(o_[0],o_[1]),  pack2(o_[2],o_[3]));
    yp[1] = make_uint2(pack2(o_[4],o_[5]),  pack2(o_[6],o_[7]));
    yp[2] = make_uint2(pack2(o_[8],o_[9]),  pack2(o_[10],o_[11]));
    yp[3] = make_uint2(pack2(o_[12],o_[13]),pack2(o_[14],o_[15]));
}

// ---------------------------------------------------------------------------
// Generic conv (layers 2-4): thread = atom, fp16 in/out, f32 accum.
// ---------------------------------------------------------------------------
template<int FIN, int FINP, int FO, int FOP, int FS>
__global__ __launch_bounds__(256) void conv_kernel(
    const unsigned short* __restrict__ x,  // (N, FINP) fp16
    const float* __restrict__ W,           // (21, FIN, FO)
    const float* __restrict__ bias,        // (21, FO)
    AdjPtrs adjp,
    unsigned short* __restrict__ y)        // (N, FOP) fp16
{
    static_assert(FS % 4 == 0 && FINP % 4 == 0 && FOP % 4 == 0, "");
    constexpr int NSF = FIN / FS;
    constexpr int TF  = FIN - NSF * FS;
    constexpr int TLD4 = (TF + 3) / 4;
    static_assert(NSF * FS + TLD4 * 4 <= FINP, "tail reads past row");

    int deg, s, c, tile;
    blk2deg(blockIdx.x, deg, s, c, tile);
    const int a = tile * NT + threadIdx.x;
    if (a >= c) return;
    const int atom = s + a;

    const int wi_a = (deg == 0) ? 20 : 2 * (deg - 1);
    const int wi_b = (deg == 0) ? 20 : 2 * deg - 1;
    const float* Wa = W + wi_a * FIN * FO;
    const float* Wb = W + wi_b * FIN * FO;

    float acc[FO];
#pragma unroll
    for (int o = 0; o < FO; ++o)
        acc[o] = bias[wi_b * FO + o] + ((deg > 0) ? bias[wi_a * FO + o] : 0.f);

    const int* myadj = (deg > 0) ? (adjp.p[deg - 1] + (size_t)a * deg) : nullptr;
    const uint2* selfrow = reinterpret_cast<const uint2*>(x + (size_t)atom * FINP);

#pragma unroll 1
    for (int st = 0; st < NSF; ++st) {
        const int f0 = st * FS;
        float r[FS];
        load_row<FS / 4>(selfrow + (f0 >> 2), r);
        fma_strip<FS, FO>(r, Wb + f0 * FO, acc);
        if (deg > 0) {
#pragma unroll
            for (int f = 0; f < FS; ++f) r[f] = 0.f;
            for (int k = 0; k < deg; ++k)
                add_row<FS / 4>(reinterpret_cast<const uint2*>(
                    x + (size_t)myadj[k] * FINP) + (f0 >> 2), r);
            fma_strip<FS, FO>(r, Wa + f0 * FO, acc);
        }
    }
    if constexpr (TF > 0) {
        constexpr int f0 = NSF * FS;
        float r[TLD4 * 4];
        load_row<TLD4>(selfrow + (f0 >> 2), r);
        fma_strip<TF, FO>(r, Wb + f0 * FO, acc);
        if (deg > 0) {
#pragma unroll
            for (int f = 0; f < TLD4 * 4; ++f) r[f] = 0.f;
            for (int k = 0; k < deg; ++k)
                add_row<TLD4>(reinterpret_cast<const uint2*>(
                    x + (size_t)myadj[k] * FINP) + (f0 >> 2), r);
            fma_strip<TF, FO>(r, Wa + f0 * FO, acc);
        }
    }

    float outv[FOP];
#pragma unroll
    for (int o = 0; o < FOP; ++o) outv[o] = (o < FO) ? selu_f(acc[o]) : 0.f;
    uint2* yp = reinterpret_cast<uint2*>(y + (size_t)atom * FOP);
#pragma unroll
    for (int v = 0; v < FOP / 4; ++v)
        yp[v] = make_uint2(pack2(outv[4*v], outv[4*v+1]),
                           pack2(outv[4*v+2], outv[4*v+3]));
}

// ---------------------------------------------------------------------------
// inverted-index build: zero -> (count fused in prep) -> scan -> scatter
// ---------------------------------------------------------------------------
__global__ __launch_bounds__(256) void zero_cnt_kernel(int* __restrict__ cnt) {
    const int i = blockIdx.x * NT + threadIdx.x;
    if (i < BATCH_C) cnt[i] = 0;
}
__global__ __launch_bounds__(1024) void scan_kernel(const int* __restrict__ cnt,
                                                    int* __restrict__ base,
                                                    int* __restrict__ cursor) {
    __shared__ int part[1024];
    const int tid = threadIdx.x;
    constexpr int CH = 24;
    const int i0 = tid * CH;
    int sum = 0;
    for (int j = 0; j < CH; ++j) { const int i = i0 + j; if (i < BATCH_C) sum += cnt[i]; }
    part[tid] = sum;
    __syncthreads();
    for (int off = 1; off < 1024; off <<= 1) {
        const int v = (tid >= off) ? part[tid - off] : 0;
        __syncthreads(); part[tid] += v; __syncthreads();
    }
    int run = part[tid] - sum;
    for (int j = 0; j < CH; ++j) {
        const int i = i0 + j;
        if (i < BATCH_C) { base[i] = run; cursor[i] = run; run += cnt[i]; }
    }
    if (tid == 1023) base[BATCH_C] = part[1023];
}
__global__ __launch_bounds__(256) void scatter_kernel(const int* __restrict__ mem,
                                                      int* __restrict__ cursor,
                                                      int* __restrict__ alist) {
    const int i = blockIdx.x * NT + threadIdx.x;
    if (i < N_ATOMS_C) { const int p = atomicAdd(&cursor[mem[i]], 1); alist[p] = i; }
}

// ---------------------------------------------------------------------------
// one wave per molecule: register sum/max over fp16 y4 rows, fused
// tanh -> 72x24 dense -> pairwise softmax
// ---------------------------------------------------------------------------
__global__ __launch_bounds__(256) void reduce_dense_kernel(
    const unsigned short* __restrict__ y4,  // (N, 36) fp16
    const int* __restrict__ base, const int* __restrict__ alist,
    const float* __restrict__ Wd, const float* __restrict__ bd,
    float* __restrict__ out)
{
    __shared__ float sW[72 * 24];
    __shared__ float sb[24];
    __shared__ float molf[4][72];

    const int tid = threadIdx.x;
    for (int i = tid; i < 72 * 24; i += NT) sW[i] = Wd[i];
    if (tid < 24) sb[tid] = bd[tid];
    __syncthreads();

    const int w = tid >> 6, lane = tid & 63;
    const int mol = blockIdx.x * 4 + w;
    const int b0 = base[mol], b1 = base[mol + 1];

    if (lane < 36) {
        float s = 0.f, mx = -INFINITY;
        for (int k = b0; k < b1; ++k) {
            const int atom = alist[k];
            const float v = __half2float(__builtin_bit_cast(__half,
                                y4[(size_t)atom * 36 + lane]));
            s += v; mx = fmaxf(mx, v);
        }
        molf[w][lane] = tanhf(s);
        molf[w][36 + lane] = tanhf(mx);
    }
    __syncthreads();

    if (lane < 24) {
        float l = sb[lane];
#pragma unroll
        for (int f = 0; f < 72; ++f) l += molf[w][f] * sW[f * 24 + lane];
        const float lp = __shfl_xor(l, 1);
        const float m2 = fmaxf(l, lp);
        const float e = expf(l - m2), ep = expf(lp - m2);
        out[(size_t)mol * 24 + lane] = e / (e + ep);
    }
}

// ---------------------------------------------------------------------------
extern "C" void kernel_launch(void* const* d_in, const int* in_sizes, int n_in,
                              void* d_out, int out_size, void* d_ws, size_t ws_size,
                              hipStream_t stream)
{
    const float* x0         = (const float*)d_in[0];
    const int*   membership = (const int*)d_in[2];
    AdjPtrs adj;
    for (int d = 0; d < 10; ++d) adj.p[d] = (const int*)d_in[3 + d];
    const float *W1=(const float*)d_in[13], *b1=(const float*)d_in[14];
    const float *W2=(const float*)d_in[15], *b2=(const float*)d_in[16];
    const float *W3=(const float*)d_in[17], *b3=(const float*)d_in[18];
    const float *W4=(const float*)d_in[19], *b4=(const float*)d_in[20];
    const float *Wd=(const float*)d_in[21], *bd=(const float*)d_in[22];

    // ws layout (bytes):
    //  A [0 .. 81.6M): z (N x 64 fp16 = 76.8M, dead after conv1)
    //                  then y2 = A[0..38.4M) (stride 32), y4 = A[38.4..81.6M) (stride 36)
    //  B [szA .. +38.4M): srow (9.6M) + y1 (19.2M, at +9.6M); after L2, y3 = B[0..38.4M)
    //  ints after B
    const size_t szA = 81600000;
    const size_t szB = 38400000;
    const size_t nInts = (size_t)N_ATOMS_C + (BATCH_C + 1) + BATCH_C + BATCH_C;
    if (ws_size < szA + szB + nInts * 4) return;

    char* base0 = (char*)d_ws;
    unsigned short* zbuf = (unsigned short*)base0;
    unsigned short* y2   = (unsigned short*)base0;                      // alias z (after conv1)
    unsigned short* y4   = (unsigned short*)(base0 + 38400000);         // alias z tail
    unsigned short* srow = (unsigned short*)(base0 + szA);
    unsigned short* y1   = (unsigned short*)(base0 + szA + 9600000);
    unsigned short* y3   = (unsigned short*)(base0 + szA);              // alias srow/y1 (after L2)
    int* alist  = (int*)(base0 + szA + szB);
    int* base   = alist + N_ATOMS_C;
    int* cursor = base + (BATCH_C + 1);
    int* cnt    = cursor + BATCH_C;

    int nblk = 0;
    for (int d = 0; d < 11; ++d) nblk += (K_COUNTS[d] + NT - 1) / NT;
    const int nb_atoms = (N_ATOMS_C + NT - 1) / NT;

    zero_cnt_kernel<<<(BATCH_C + NT - 1) / NT, NT, 0, stream>>>(cnt);
    prep_kernel<<<nblk, NT, 0, stream>>>(x0, W1, b1, membership, cnt, zbuf, srow);
    scan_kernel<<<1, 1024, 0, stream>>>(cnt, base, cursor);
    scatter_kernel<<<nb_atoms, NT, 0, stream>>>(membership, cursor, alist);

    conv1_kernel<<<nblk, NT, 0, stream>>>(x0, zbuf, srow, W1, adj, y1);
    conv_kernel<15,16,20,32,16><<<nblk, NT, 0, stream>>>(y1, W2, b2, adj, y2);
    conv_kernel<20,32,27,32,32><<<nblk, NT, 0, stream>>>(y2, W3, b3, adj, y3);
    conv_kernel<27,32,36,36,32><<<nblk, NT, 0, stream>>>(y3, W4, b4, adj, y4);

    reduce_dense_kernel<<<BATCH_C / 4, NT, 0, stream>>>(y4, base, alist, Wd, bd, (float*)d_out);
}

// Round 12
// 660.796 us; speedup vs baseline: 1.0582x; 1.0288x over previous
//
#include <hip/hip_runtime.h>
#include <hip/hip_fp16.h>
#include <cstdint>

#define NT 256
#define N_ATOMS_C 600000
#define BATCH_C 24000

constexpr int K_COUNTS[11] = {10000,130000,170000,160000,100000,15000,5000,2500,2500,2500,2500};
constexpr int K_STARTS[11] = {0,10000,140000,310000,470000,570000,585000,590000,592500,595000,597500};
// heavy-degree-first dispatch order
constexpr int DORD[11] = {10,9,8,7,6,5,4,3,2,1,0};

struct AdjPtrs { const int* p[10]; };

typedef _Float16 h2 __attribute__((ext_vector_type(2)));

__device__ __forceinline__ float selu_f(float x) {
    const float scale = 1.0507009873554805f;
    const float alpha = 1.6732632423543772f;
    return scale * (x > 0.f ? x : alpha * expm1f(x));
}

__device__ __forceinline__ float2 up2(unsigned u) {
    const __half2 h = __builtin_bit_cast(__half2, u);
    return __half22float2(h);
}
__device__ __forceinline__ unsigned pack2(float a, float b) {
    const __half2 h = __float22half2_rn(make_float2(a, b));
    return __builtin_bit_cast(unsigned, h);
}

// fp16 pair dot-accumulate: acc += a.x*b.x + a.y*b.y (f32 accumulate)
__device__ __forceinline__ float fdot2u(unsigned a, unsigned b, float c) {
#if __has_builtin(__builtin_amdgcn_fdot2)
    return __builtin_amdgcn_fdot2(__builtin_bit_cast(h2, a),
                                  __builtin_bit_cast(h2, b), c, false);
#else
    const float2 av = up2(a), bv = up2(b);
    return fmaf(av.y, bv.y, fmaf(av.x, bv.x, c));
#endif
}

template<int NLD4>
__device__ __forceinline__ void load_row(const uint2* __restrict__ p, float* r) {
#pragma unroll
    for (int v = 0; v < NLD4; ++v) {
        const uint2 t = p[v];
        const float2 a = up2(t.x), b = up2(t.y);
        r[4*v] = a.x; r[4*v+1] = a.y; r[4*v+2] = b.x; r[4*v+3] = b.y;
    }
}
template<int NLD4>
__device__ __forceinline__ void add_row(const uint2* __restrict__ p, float* r) {
#pragma unroll
    for (int v = 0; v < NLD4; ++v) {
        const uint2 t = p[v];
        const float2 a = up2(t.x), b = up2(t.y);
        r[4*v] += a.x; r[4*v+1] += a.y; r[4*v+2] += b.x; r[4*v+3] += b.y;
    }
}
template<int NF, int FO>
__device__ __forceinline__ void fma_strip(const float* r, const float* __restrict__ w,
                                          float* acc) {
#pragma unroll
    for (int f = 0; f < NF; ++f)
#pragma unroll
        for (int o = 0; o < FO; ++o)
            acc[o] = fmaf(r[f], w[f * FO + o], acc[o]);
}

// block -> (degree, segment start, count, tile index within segment)
__device__ __forceinline__ void blk2deg(int blk, int& deg, int& s, int& cnt, int& tile) {
    deg = 0; s = 0; cnt = 0; tile = 0;
#pragma unroll
    for (int di = 0; di < 11; ++di) {
        const int d = DORD[di];
        const int nb = (K_COUNTS[d] + NT - 1) / NT;
        if (blk < nb) { deg = d; s = K_STARTS[d]; cnt = K_COUNTS[d]; tile = blk; return; }
        blk -= nb;
    }
}

// ---------------------------------------------------------------------------
// wpack: W1 (21,75,15) f32 -> fp16 feature-pair packed: wpk[(j*38+u)*15+o] =
// half2(W[j][2u][o], W[j][2u+1][o] or 0). One-off, trivial.
// ---------------------------------------------------------------------------
__global__ __launch_bounds__(256) void wpack_kernel(const float* __restrict__ W,
                                                    unsigned* __restrict__ wpk)
{
    const int idx = blockIdx.x * NT + threadIdx.x;
    if (idx >= 21 * 38 * 15) return;
    const int j = idx / (38 * 15), rem = idx - j * (38 * 15);
    const int u = rem / 15, o = rem - u * 15;
    const float a = W[(j * 75 + 2 * u) * 15 + o];
    const float b = (2 * u + 1 < 75) ? W[(j * 75 + 2 * u + 1) * 15 + o] : 0.f;
    wpk[idx] = pack2(a, b);
}

// ---------------------------------------------------------------------------
// prep: per atom, z_d = x0 @ W[2(d-1)] (d=1..4) into 4 planes (N,16) fp16, and
// s = x0 @ Wb(own deg) + biases (fp16, 32B). Row staged in LDS once, held in
// 38 u32 VGPRs; 5 projections SEQUENTIAL (15 live accs each — no spill);
// inner loop = v_dot2_f32_f16 with packed-fp16 wave-uniform weights (s_load),
// FULLY unrolled so the compiler batches the weight loads (r11: unroll-2 ->
// per-pair lgkmcnt stall, 320us at 21% VALUBusy).
// ---------------------------------------------------------------------------
__global__ __launch_bounds__(256) void prep_kernel(
    const float* __restrict__ x0,    // (N, 75) f32
    const unsigned* __restrict__ wpk,// (21, 38, 15) packed fp16 pairs
    const float* __restrict__ bias,  // (21, 15)
    const int* __restrict__ mem,
    int* __restrict__ cnt,
    unsigned short* __restrict__ z,  // 4 planes of (N, 16) fp16
    unsigned short* __restrict__ srow) // (N, 16) fp16
{
    __shared__ unsigned short sx[NT * 78];   // 39.9 KB; 39-dword rows (odd)

    int deg, s, c, tile;
    blk2deg(blockIdx.x, deg, s, c, tile);
    const int a0 = tile * NT;
    const int na = min(NT, c - a0);
    const int tid = threadIdx.x;

    // cooperative coalesced stage: na*75 f32 -> fp16 LDS; zero the pad short
    const float* src = x0 + (size_t)(s + a0) * 75;
    for (int i = tid; i < na * 75; i += NT) {
        const int j = i / 75, f = i - j * 75;
        sx[j * 78 + f] = __builtin_bit_cast(unsigned short, __float2half_rn(src[i]));
    }
    for (int j = tid; j < na; j += NT) sx[j * 78 + 75] = 0;
    __syncthreads();

    const int a = a0 + tid;
    if (a >= c) return;                      // no barriers after this point
    const int atom = s + a;

    // pull the whole row into registers (38 u32 = 76 feats incl. zero pad)
    unsigned xr[38];
    {
        const unsigned* row32 = reinterpret_cast<const unsigned*>(sx + tid * 78);
#pragma unroll
        for (int u = 0; u < 38; ++u) xr[u] = row32[u];
    }

    const int wi_b = deg ? (2 * deg - 1) : 20;

#pragma unroll 1
    for (int p = 0; p < 5; ++p) {
        const int wi = (p < 4) ? 2 * p : wi_b;
        const unsigned* wp = wpk + wi * (38 * 15);

        float acc[15];
        if (p < 4) {
#pragma unroll
            for (int o = 0; o < 15; ++o) acc[o] = 0.f;
        } else {
#pragma unroll
            for (int o = 0; o < 15; ++o)
                acc[o] = bias[wi_b * 15 + o] + (deg ? bias[2 * (deg - 1) * 15 + o] : 0.f);
        }

#pragma unroll
        for (int u = 0; u < 38; ++u) {
            const unsigned xv = xr[u];
#pragma unroll
            for (int o = 0; o < 15; ++o)
                acc[o] = fdot2u(xv, wp[u * 15 + o], acc[o]);
        }

        unsigned short* outp = (p < 4)
            ? (z + (size_t)p * (N_ATOMS_C * 16) + (size_t)atom * 16)
            : (srow + (size_t)atom * 16);
        uint4* o4 = reinterpret_cast<uint4*>(outp);
        o4[0] = make_uint4(pack2(acc[0], acc[1]),  pack2(acc[2], acc[3]),
                           pack2(acc[4], acc[5]),  pack2(acc[6], acc[7]));
        o4[1] = make_uint4(pack2(acc[8], acc[9]),  pack2(acc[10], acc[11]),
                           pack2(acc[12], acc[13]), pack2(acc[14], 0.f));
    }

    atomicAdd(&cnt[mem[atom]], 1);
}

// ---------------------------------------------------------------------------
// conv1: deg<=4 -> s + sum of gathered 32-B rows from z plane (deg-1).
//        deg>=5 -> s + full x0-row gathers vs Wa (rare: 190K rows).
// ---------------------------------------------------------------------------
__global__ __launch_bounds__(256) void conv1_kernel(
    const float* __restrict__ x0,
    const unsigned short* __restrict__ z,     // 4 planes of (N,16)
    const unsigned short* __restrict__ srow,
    const float* __restrict__ W,
    AdjPtrs adjp,
    unsigned short* __restrict__ y1)  // (N, 16) fp16
{
    int deg, s, c, tile;
    blk2deg(blockIdx.x, deg, s, c, tile);
    const int a = tile * NT + threadIdx.x;
    if (a >= c) return;
    const int atom = s + a;

    float acc[15];
    {
        const uint2* sp = reinterpret_cast<const uint2*>(srow + (size_t)atom * 16);
        float r[16];
        load_row<4>(sp, r);
#pragma unroll
        for (int o = 0; o < 15; ++o) acc[o] = r[o];
    }

    if (deg >= 1 && deg <= 4) {
        const unsigned short* zd = z + (size_t)(deg - 1) * (N_ATOMS_C * 16);
        const int* ad = adjp.p[deg - 1] + (size_t)a * deg;
        int nb[4];
#pragma unroll
        for (int k = 0; k < 4; ++k) nb[k] = ad[k < deg ? k : 0];
        uint2 t[4][4];
#pragma unroll
        for (int k = 0; k < 4; ++k) {
            const uint2* p = reinterpret_cast<const uint2*>(zd + (size_t)nb[k] * 16);
#pragma unroll
            for (int v = 0; v < 4; ++v) t[k][v] = p[v];
        }
#pragma unroll
        for (int k = 0; k < 4; ++k) {
            if (k < deg) {
                float r[16];
#pragma unroll
                for (int v = 0; v < 4; ++v) {
                    const float2 lo = up2(t[k][v].x), hi = up2(t[k][v].y);
                    r[4*v] = lo.x; r[4*v+1] = lo.y; r[4*v+2] = hi.x; r[4*v+3] = hi.y;
                }
#pragma unroll
                for (int o = 0; o < 15; ++o) acc[o] += r[o];
            }
        }
    } else if (deg >= 5) {
        const float* Wa = W + 2 * (deg - 1) * 1125;
        const int* ad = adjp.p[deg - 1] + (size_t)a * deg;
#pragma unroll 1
        for (int st = 0; st < 3; ++st) {
            float r[25];
#pragma unroll
            for (int j = 0; j < 25; ++j) r[j] = 0.f;
            for (int k = 0; k < deg; ++k) {
                const float* xr = x0 + (size_t)ad[k] * 75 + st * 25;
#pragma unroll
                for (int j = 0; j < 25; ++j) r[j] += xr[j];
            }
            fma_strip<25, 15>(r, Wa + st * 25 * 15, acc);
        }
    }

    uint2* yp = reinterpret_cast<uint2*>(y1 + (size_t)atom * 16);
    float o_[16];
#pragma unroll
    for (int o = 0; o < 16; ++o) o_[o] = (o < 15) ? selu_f(acc[o]) : 0.f;
    yp[0] = make_uint2(pack2(o_[0],o_[1]),  pack2(o_[2],o_[3]));
    yp[1] = make_uint2(pack2(o_[4],o_[5]),  pack2(o_[6],o_[7]));
    yp[2] = make_uint2(pack2(o_[8],o_[9]),  pack2(o_[10],o_[11]));
    yp[3] = make_uint2(pack2(o_[12],o_[13]),pack2(o_[14],o_[15]));
}

// ---------------------------------------------------------------------------
// Generic conv (layers 2-4): thread = atom, fp16 in/out, f32 accum.
// ---------------------------------------------------------------------------
template<int FIN, int FINP, int FO, int FOP, int FS>
__global__ __launch_bounds__(256) void conv_kernel(
    const unsigned short* __restrict__ x,  // (N, FINP) fp16
    const float* __restrict__ W,           // (21, FIN, FO)
    const float* __restrict__ bias,        // (21, FO)
    AdjPtrs adjp,
    unsigned short* __restrict__ y)        // (N, FOP) fp16
{
    static_assert(FS % 4 == 0 && FINP % 4 == 0 && FOP % 4 == 0, "");
    constexpr int NSF = FIN / FS;
    constexpr int TF  = FIN - NSF * FS;
    constexpr int TLD4 = (TF + 3) / 4;
    static_assert(NSF * FS + TLD4 * 4 <= FINP, "tail reads past row");

    int deg, s, c, tile;
    blk2deg(blockIdx.x, deg, s, c, tile);
    const int a = tile * NT + threadIdx.x;
    if (a >= c) return;
    const int atom = s + a;

    const int wi_a = (deg == 0) ? 20 : 2 * (deg - 1);
    const int wi_b = (deg == 0) ? 20 : 2 * deg - 1;
    const float* Wa = W + wi_a * FIN * FO;
    const float* Wb = W + wi_b * FIN * FO;

    float acc[FO];
#pragma unroll
    for (int o = 0; o < FO; ++o)
        acc[o] = bias[wi_b * FO + o] + ((deg > 0) ? bias[wi_a * FO + o] : 0.f);

    const int* myadj = (deg > 0) ? (adjp.p[deg - 1] + (size_t)a * deg) : nullptr;
    const uint2* selfrow = reinterpret_cast<const uint2*>(x + (size_t)atom * FINP);

#pragma unroll 1
    for (int st = 0; st < NSF; ++st) {
        const int f0 = st * FS;
        float r[FS];
        load_row<FS / 4>(selfrow + (f0 >> 2), r);
        fma_strip<FS, FO>(r, Wb + f0 * FO, acc);
        if (deg > 0) {
#pragma unroll
            for (int f = 0; f < FS; ++f) r[f] = 0.f;
            for (int k = 0; k < deg; ++k)
                add_row<FS / 4>(reinterpret_cast<const uint2*>(
                    x + (size_t)myadj[k] * FINP) + (f0 >> 2), r);
            fma_strip<FS, FO>(r, Wa + f0 * FO, acc);
        }
    }
    if constexpr (TF > 0) {
        constexpr int f0 = NSF * FS;
        float r[TLD4 * 4];
        load_row<TLD4>(selfrow + (f0 >> 2), r);
        fma_strip<TF, FO>(r, Wb + f0 * FO, acc);
        if (deg > 0) {
#pragma unroll
            for (int f = 0; f < TLD4 * 4; ++f) r[f] = 0.f;
            for (int k = 0; k < deg; ++k)
                add_row<TLD4>(reinterpret_cast<const uint2*>(
                    x + (size_t)myadj[k] * FINP) + (f0 >> 2), r);
            fma_strip<TF, FO>(r, Wa + f0 * FO, acc);
        }
    }

    float outv[FOP];
#pragma unroll
    for (int o = 0; o < FOP; ++o) outv[o] = (o < FO) ? selu_f(acc[o]) : 0.f;
    uint2* yp = reinterpret_cast<uint2*>(y + (size_t)atom * FOP);
#pragma unroll
    for (int v = 0; v < FOP / 4; ++v)
        yp[v] = make_uint2(pack2(outv[4*v], outv[4*v+1]),
                           pack2(outv[4*v+2], outv[4*v+3]));
}

// ---------------------------------------------------------------------------
// inverted-index build: zero -> (count fused in prep) -> scan -> scatter
// ---------------------------------------------------------------------------
__global__ __launch_bounds__(256) void zero_cnt_kernel(int* __restrict__ cnt) {
    const int i = blockIdx.x * NT + threadIdx.x;
    if (i < BATCH_C) cnt[i] = 0;
}
__global__ __launch_bounds__(1024) void scan_kernel(const int* __restrict__ cnt,
                                                    int* __restrict__ base,
                                                    int* __restrict__ cursor) {
    __shared__ int part[1024];
    const int tid = threadIdx.x;
    constexpr int CH = 24;
    const int i0 = tid * CH;
    int sum = 0;
    for (int j = 0; j < CH; ++j) { const int i = i0 + j; if (i < BATCH_C) sum += cnt[i]; }
    part[tid] = sum;
    __syncthreads();
    for (int off = 1; off < 1024; off <<= 1) {
        const int v = (tid >= off) ? part[tid - off] : 0;
        __syncthreads(); part[tid] += v; __syncthreads();
    }
    int run = part[tid] - sum;
    for (int j = 0; j < CH; ++j) {
        const int i = i0 + j;
        if (i < BATCH_C) { base[i] = run; cursor[i] = run; run += cnt[i]; }
    }
    if (tid == 1023) base[BATCH_C] = part[1023];
}
__global__ __launch_bounds__(256) void scatter_kernel(const int* __restrict__ mem,
                                                      int* __restrict__ cursor,
                                                      int* __restrict__ alist) {
    const int i = blockIdx.x * NT + threadIdx.x;
    if (i < N_ATOMS_C) { const int p = atomicAdd(&cursor[mem[i]], 1); alist[p] = i; }
}

// ---------------------------------------------------------------------------
// one wave per molecule: register sum/max over fp16 y4 rows, fused
// tanh -> 72x24 dense -> pairwise softmax
// ---------------------------------------------------------------------------
__global__ __launch_bounds__(256) void reduce_dense_kernel(
    const unsigned short* __restrict__ y4,  // (N, 36) fp16
    const int* __restrict__ base, const int* __restrict__ alist,
    const float* __restrict__ Wd, const float* __restrict__ bd,
    float* __restrict__ out)
{
    __shared__ float sW[72 * 24];
    __shared__ float sb[24];
    __shared__ float molf[4][72];

    const int tid = threadIdx.x;
    for (int i = tid; i < 72 * 24; i += NT) sW[i] = Wd[i];
    if (tid < 24) sb[tid] = bd[tid];
    __syncthreads();

    const int w = tid >> 6, lane = tid & 63;
    const int mol = blockIdx.x * 4 + w;
    const int b0 = base[mol], b1 = base[mol + 1];

    if (lane < 36) {
        float s = 0.f, mx = -INFINITY;
        for (int k = b0; k < b1; ++k) {
            const int atom = alist[k];
            const float v = __half2float(__builtin_bit_cast(__half,
                                y4[(size_t)atom * 36 + lane]));
            s += v; mx = fmaxf(mx, v);
        }
        molf[w][lane] = tanhf(s);
        molf[w][36 + lane] = tanhf(mx);
    }
    __syncthreads();

    if (lane < 24) {
        float l = sb[lane];
#pragma unroll
        for (int f = 0; f < 72; ++f) l += molf[w][f] * sW[f * 24 + lane];
        const float lp = __shfl_xor(l, 1);
        const float m2 = fmaxf(l, lp);
        const float e = expf(l - m2), ep = expf(lp - m2);
        out[(size_t)mol * 24 + lane] = e / (e + ep);
    }
}

// ---------------------------------------------------------------------------
extern "C" void kernel_launch(void* const* d_in, const int* in_sizes, int n_in,
                              void* d_out, int out_size, void* d_ws, size_t ws_size,
                              hipStream_t stream)
{
    const float* x0         = (const float*)d_in[0];
    const int*   membership = (const int*)d_in[2];
    AdjPtrs adj;
    for (int d = 0; d < 10; ++d) adj.p[d] = (const int*)d_in[3 + d];
    const float *W1=(const float*)d_in[13], *b1=(const float*)d_in[14];
    const float *W2=(const float*)d_in[15], *b2=(const float*)d_in[16];
    const float *W3=(const float*)d_in[17], *b3=(const float*)d_in[18];
    const float *W4=(const float*)d_in[19], *b4=(const float*)d_in[20];
    const float *Wd=(const float*)d_in[21], *bd=(const float*)d_in[22];

    // ws layout (bytes):
    //  A [0 .. 81.6M): z planes 4 x (N,16) fp16 = 76.8M (dead after conv1);
    //                  then y2 = A[0..38.4M) (stride 32), y4 = A[38.4..81.6M)
    //  B [szA .. +38.4M): srow (19.2M) + y1 (19.2M at +19.2M);
    //                  after L2 both dead -> y3 = B[0..38.4M)
    //  ints after B; wpk (packed fp16 weights, 48KB) after ints
    const size_t szA = 81600000;
    const size_t szB = 38400000;
    const size_t nInts = (size_t)N_ATOMS_C + (BATCH_C + 1) + BATCH_C + BATCH_C;
    const size_t wpkOff = szA + szB + nInts * 4;
    if (ws_size < wpkOff + 21 * 38 * 15 * 4) return;

    char* base0 = (char*)d_ws;
    unsigned short* zbuf = (unsigned short*)base0;
    unsigned short* y2   = (unsigned short*)base0;                      // alias A
    unsigned short* y4   = (unsigned short*)(base0 + 38400000);         // alias A tail
    unsigned short* srow = (unsigned short*)(base0 + szA);
    unsigned short* y1   = (unsigned short*)(base0 + szA + 19200000);
    unsigned short* y3   = (unsigned short*)(base0 + szA);              // alias B after L2
    int* alist  = (int*)(base0 + szA + szB);
    int* base   = alist + N_ATOMS_C;
    int* cursor = base + (BATCH_C + 1);
    int* cnt    = cursor + BATCH_C;
    unsigned* wpk = (unsigned*)(base0 + wpkOff);

    int nblk = 0;
    for (int d = 0; d < 11; ++d) nblk += (K_COUNTS[d] + NT - 1) / NT;
    const int nb_atoms = (N_ATOMS_C + NT - 1) / NT;

    zero_cnt_kernel<<<(BATCH_C + NT - 1) / NT, NT, 0, stream>>>(cnt);
    wpack_kernel<<<(21 * 38 * 15 + NT - 1) / NT, NT, 0, stream>>>(W1, wpk);
    prep_kernel<<<nblk, NT, 0, stream>>>(x0, wpk, b1, membership, cnt, zbuf, srow);
    scan_kernel<<<1, 1024, 0, stream>>>(cnt, base, cursor);
    scatter_kernel<<<nb_atoms, NT, 0, stream>>>(membership, cursor, alist);

    conv1_kernel<<<nblk, NT, 0, stream>>>(x0, zbuf, srow, W1, adj, y1);
    conv_kernel<15,16,20,32,16><<<nblk, NT, 0, stream>>>(y1, W2, b2, adj, y2);
    conv_kernel<20,32,27,32,32><<<nblk, NT, 0, stream>>>(y2, W3, b3, adj, y3);
    conv_kernel<27,32,36,36,32><<<nblk, NT, 0, stream>>>(y3, W4, b4, adj, y4);

    reduce_dense_kernel<<<BATCH_C / 4, NT, 0, stream>>>(y4, base, alist, Wd, bd, (float*)d_out);
}